// Round 5
// baseline (114.795 us; speedup 1.0000x reference)
//
#include <hip/hip_runtime.h>
#include <math.h>

// P2V: out[b,dhw] = top2-margin over n of softmax_n( |s2| * exp(-|s1| * dist) )
// dist = |x|^2 + |g|^2 - 2 x.g
//
// Round 3 kernel, resubmitted (rounds 3 & 4 were broker timeouts; never ran):
// the per-n table is WAVE-UNIFORM data; LDS broadcast still costs a full
// ds_read_b128 (12 cyc) on the per-CU LDS port -> 98K cyc/CU was the round-2
// bottleneck. Move the table to global memory (precompute kernel into d_ws)
// and read it with uniform indices: compiler lowers to s_load_dwordx16 on the
// scalar pipe (sK$), freeing both the LDS port and VALU issue slots.
//
// Math (unchanged from round 2): q_n = -c1|x_n|^2 + 2c1(x_n.g), c1=log2e*|s1|
//   v_n = Ct*2^q_n, Ct = |s2|*2^(-c1|g|^2); top-2 of v == top-2 of q.
//   S = sum_n 2^(ECt*2^q_n - Ls2)  (shift by bound v<=|s2|, no max pre-pass)
//   out = 2^(ECt*u0 - Ls2)*(1 - 2^(ECt*(u1-u0))) / S.

#define LOG2E 1.44269504088896340736f

__global__ void build_tab(const float* __restrict__ xyz,
                          const float* __restrict__ s1,
                          float4* __restrict__ tab) {
    const int i = blockIdx.x * 256 + threadIdx.x;   // 0..4095
    const int b = i >> 10, n = i & 1023;
    const float c1 = LOG2E * fabsf(s1[0]);
    const float* xb = xyz + b * 3072;
    const float x = xb[n], y = xb[1024 + n], z = xb[2048 + n];
    const float x2 = fmaf(x, x, fmaf(y, y, z * z));
    tab[i] = make_float4(-c1 * x2, 2.f * c1 * x, 2.f * c1 * y, 2.f * c1 * z);
}

__global__ __launch_bounds__(256, 2) void p2v_kernel(
    const float4* __restrict__ tab,  // (B=4, N=1024) uniform table in d_ws
    const float* __restrict__ grid,  // (C=3, 32768)
    const float* __restrict__ s1,
    const float* __restrict__ s2,
    float* __restrict__ out)         // (B=4, 32768)
{
    const int tid = threadIdx.x;
    const int b   = blockIdx.x >> 7;                 // 128 blocks per b
    const int dhw = ((blockIdx.x & 127) << 8) + tid; // coalesced

    const float s1a = fabsf(s1[0]);
    const float s2a = fabsf(s2[0]);
    const float c1  = LOG2E * s1a;
    const float Ls2 = LOG2E * s2a;

    const float g0 = grid[dhw];
    const float g1 = grid[32768 + dhw];
    const float g2 = grid[65536 + dhw];
    const float Ct  = s2a * __builtin_amdgcn_exp2f(-c1 * fmaf(g0, g0, fmaf(g1, g1, g2 * g2)));
    const float ECt = LOG2E * Ct;

    const float4* tb = tab + (b << 10);

    float t0 = -INFINITY, t1 = -INFINITY;
    float Sa0 = 0.f, Sa1 = 0.f, Sa2 = 0.f, Sa3 = 0.f;

    for (int n0 = 0; n0 < 1024; n0 += 16) {
        #pragma unroll
        for (int j = 0; j < 16; ++j) {
            const float4 a = tb[n0 + j];             // uniform -> s_load
            const float q = fmaf(g0, a.y, fmaf(g1, a.z, fmaf(g2, a.w, a.x)));
            t1 = __builtin_amdgcn_fmed3f(t0, t1, q); // new 2nd-largest
            t0 = fmaxf(t0, q);                       // new largest
            const float w = __builtin_amdgcn_exp2f(
                fmaf(ECt, __builtin_amdgcn_exp2f(q), -Ls2));
            if ((j & 3) == 0) Sa0 += w;
            else if ((j & 3) == 1) Sa1 += w;
            else if ((j & 3) == 2) Sa2 += w;
            else Sa3 += w;
        }
    }
    const float S = (Sa0 + Sa1) + (Sa2 + Sa3);

    const float u0 = __builtin_amdgcn_exp2f(t0);
    const float u1 = __builtin_amdgcn_exp2f(t1);
    const float w0 = __builtin_amdgcn_exp2f(fmaf(ECt, u0, -Ls2)); // exp(v0-|s2|)
    const float num = w0 * (1.f - __builtin_amdgcn_exp2f(ECt * (u1 - u0)));
    out[b * 32768 + dhw] = num / S;
}

extern "C" void kernel_launch(void* const* d_in, const int* in_sizes, int n_in,
                              void* d_out, int out_size, void* d_ws, size_t ws_size,
                              hipStream_t stream) {
    const float* xyz  = (const float*)d_in[0];
    const float* grid = (const float*)d_in[1];
    const float* s1   = (const float*)d_in[2];
    const float* s2   = (const float*)d_in[3];
    float* out        = (float*)d_out;
    float4* tab       = (float4*)d_ws;               // 4096 * 16 B = 64 KB

    hipLaunchKernelGGL(build_tab, dim3(16), dim3(256), 0, stream, xyz, s1, tab);
    hipLaunchKernelGGL(p2v_kernel, dim3(512), dim3(256), 0, stream,
                       tab, grid, s1, s2, out);
}

// Round 6
// 105.527 us; speedup vs baseline: 1.0878x; 1.0878x over previous
//
#include <hip/hip_runtime.h>
#include <math.h>

// P2V: out[b,dhw] = top2-margin over n of softmax_n( |s2| * exp(-|s1| * dist) )
// dist = |x|^2 + |g|^2 - 2 x.g
//
// Round 6: back to LDS (R5's scalar path stalled on s_load latency: 59.8us).
// R2 was LDS-PORT-bound: waves/CU x 12cyc ds_read_b128 per n (96/113 cyc).
// Port demand is independent of outputs/thread -> halve waves, double work:
// 256 blocks x 256 threads x 2 outputs/thread = 1 block/CU, 4 waves/CU,
// LDS 48 cyc/CU/n. Parity-split top-2 + S accumulators keep the dependency
// chain off the critical path at 1 wave/SIMD; 8-deep unroll pipelines loads.
//
// Math (unchanged): q_n = -c1|x_n|^2 + 2c1(x_n.g), c1=log2e*|s1|
//   v_n = Ct*2^q_n, Ct = |s2|*2^(-c1|g|^2); top-2 of v == top-2 of q.
//   S = sum_n 2^(ECt*2^q_n - Ls2)  (shift by bound v<=|s2|, no max pre-pass)
//   out = 2^(ECt*u0 - Ls2)*(1 - 2^(ECt*(u1-u0))) / S.

#define LOG2E 1.44269504088896340736f

__global__ __launch_bounds__(256, 1) void p2v_kernel(
    const float* __restrict__ xyz,   // (B=4, C=3, N=1024)
    const float* __restrict__ grid,  // (C=3, 32768)
    const float* __restrict__ s1,
    const float* __restrict__ s2,
    float* __restrict__ out)         // (B=4, 32768)
{
    __shared__ float4 A[1024];       // 16 KB per-n table for this block's b

    const int tid  = threadIdx.x;
    const int b    = blockIdx.x >> 6;                  // 64 blocks per b
    const int dhw0 = ((blockIdx.x & 63) << 9) + tid;   // chunk*512 + tid
    const int dhw1 = dhw0 + 256;

    const float s1a = fabsf(s1[0]);
    const float s2a = fabsf(s2[0]);
    const float c1  = LOG2E * s1a;
    const float Ls2 = LOG2E * s2a;

    const float* xb = xyz + b * 3072;
    #pragma unroll
    for (int i = 0; i < 4; ++i) {
        const int n = tid + i * 256;
        const float x = xb[n], y = xb[1024 + n], z = xb[2048 + n];
        const float x2 = fmaf(x, x, fmaf(y, y, z * z));
        A[n] = make_float4(-c1 * x2, 2.f * c1 * x, 2.f * c1 * y, 2.f * c1 * z);
    }
    __syncthreads();

    // two outputs per thread
    const float ga0 = grid[dhw0], ga1 = grid[32768 + dhw0], ga2 = grid[65536 + dhw0];
    const float gb0 = grid[dhw1], gb1 = grid[32768 + dhw1], gb2 = grid[65536 + dhw1];
    const float ECa = LOG2E * s2a *
        __builtin_amdgcn_exp2f(-c1 * fmaf(ga0, ga0, fmaf(ga1, ga1, ga2 * ga2)));
    const float ECb = LOG2E * s2a *
        __builtin_amdgcn_exp2f(-c1 * fmaf(gb0, gb0, fmaf(gb1, gb1, gb2 * gb2)));

    // parity-split top-2 and sum accumulators (ILP at 1 wave/SIMD)
    float t0aE = -INFINITY, t1aE = -INFINITY, t0aO = -INFINITY, t1aO = -INFINITY;
    float t0bE = -INFINITY, t1bE = -INFINITY, t0bO = -INFINITY, t1bO = -INFINITY;
    float SaE = 0.f, SaO = 0.f, SbE = 0.f, SbO = 0.f;

    for (int n0 = 0; n0 < 1024; n0 += 8) {
        float4 r[8];
        #pragma unroll
        for (int j = 0; j < 8; ++j) r[j] = A[n0 + j];
        #pragma unroll
        for (int j = 0; j < 8; ++j) {
            const float4 a = r[j];
            const float qa = fmaf(ga0, a.y, fmaf(ga1, a.z, fmaf(ga2, a.w, a.x)));
            const float qb = fmaf(gb0, a.y, fmaf(gb1, a.z, fmaf(gb2, a.w, a.x)));
            if (j & 1) {
                t1aO = __builtin_amdgcn_fmed3f(t0aO, t1aO, qa); t0aO = fmaxf(t0aO, qa);
                t1bO = __builtin_amdgcn_fmed3f(t0bO, t1bO, qb); t0bO = fmaxf(t0bO, qb);
            } else {
                t1aE = __builtin_amdgcn_fmed3f(t0aE, t1aE, qa); t0aE = fmaxf(t0aE, qa);
                t1bE = __builtin_amdgcn_fmed3f(t0bE, t1bE, qb); t0bE = fmaxf(t0bE, qb);
            }
            const float wa = __builtin_amdgcn_exp2f(
                fmaf(ECa, __builtin_amdgcn_exp2f(qa), -Ls2));
            const float wb = __builtin_amdgcn_exp2f(
                fmaf(ECb, __builtin_amdgcn_exp2f(qb), -Ls2));
            if (j & 1) { SaO += wa; SbO += wb; }
            else       { SaE += wa; SbE += wb; }
        }
    }

    // merge parity-split top-2: top0 = max(t0E,t0O); top1 = max(min(t0E,t0O), t1E, t1O)
    const float t0a = fmaxf(t0aE, t0aO);
    const float t1a = fmaxf(fminf(t0aE, t0aO), fmaxf(t1aE, t1aO));
    const float t0b = fmaxf(t0bE, t0bO);
    const float t1b = fmaxf(fminf(t0bE, t0bO), fmaxf(t1bE, t1bO));
    const float Sa = SaE + SaO;
    const float Sb = SbE + SbO;

    const float u0a = __builtin_amdgcn_exp2f(t0a);
    const float u1a = __builtin_amdgcn_exp2f(t1a);
    const float w0a = __builtin_amdgcn_exp2f(fmaf(ECa, u0a, -Ls2));
    const float numa = w0a * (1.f - __builtin_amdgcn_exp2f(ECa * (u1a - u0a)));

    const float u0b = __builtin_amdgcn_exp2f(t0b);
    const float u1b = __builtin_amdgcn_exp2f(t1b);
    const float w0b = __builtin_amdgcn_exp2f(fmaf(ECb, u0b, -Ls2));
    const float numb = w0b * (1.f - __builtin_amdgcn_exp2f(ECb * (u1b - u0b)));

    float* ob = out + b * 32768;
    ob[dhw0] = numa / Sa;
    ob[dhw1] = numb / Sb;
}

extern "C" void kernel_launch(void* const* d_in, const int* in_sizes, int n_in,
                              void* d_out, int out_size, void* d_ws, size_t ws_size,
                              hipStream_t stream) {
    const float* xyz  = (const float*)d_in[0];
    const float* grid = (const float*)d_in[1];
    const float* s1   = (const float*)d_in[2];
    const float* s2   = (const float*)d_in[3];
    float* out        = (float*)d_out;
    hipLaunchKernelGGL(p2v_kernel, dim3(256), dim3(256), 0, stream,
                       xyz, grid, s1, s2, out);
}

// Round 7
// 99.308 us; speedup vs baseline: 1.1559x; 1.0626x over previous
//
#include <hip/hip_runtime.h>
#include <math.h>

// P2V: out[b,dhw] = top2-margin over n of softmax_n( |s2| * exp(-|s1| * dist) )
// dist = |x|^2 + |g|^2 - 2 x.g
//
// Round 7: all-round fit shows the bottleneck is v_exp_f32 at ~22 cyc/wave64
// (dependent chains expose trans latency; theoretical pipelined rate is
// ~8 cyc). Fix: phase-batched inner loop - 8 independent exps per phase in
// statically-indexed register arrays so the scheduler can issue them
// back-to-back. R2 config otherwise (512x256, 1 out/thread, LDS table).
//
// Math: q_n = -c1|x_n|^2 + 2c1(x_n.g), c1=log2e*|s1|; v_n = Ct*2^q_n,
//   Ct=|s2|*2^(-c1|g|^2); top-2 of v == top-2 of q (monotone).
//   S = sum_n 2^(ECt*2^q_n - Ls2)   (shift by bound v<=|s2|; no max pre-pass)
//   out = 2^(ECt*u0 - Ls2)*(1 - 2^(ECt*(u1-u0))) / S.

#define LOG2E 1.44269504088896340736f

__global__ __launch_bounds__(256, 2) void p2v_kernel(
    const float* __restrict__ xyz,   // (B=4, C=3, N=1024)
    const float* __restrict__ grid,  // (C=3, 32768)
    const float* __restrict__ s1,
    const float* __restrict__ s2,
    float* __restrict__ out)         // (B=4, 32768)
{
    __shared__ float4 A[1024];       // 16 KB per-n table for this block's b

    const int tid = threadIdx.x;
    const int b   = blockIdx.x >> 7;                 // 128 blocks per b
    const int dhw = ((blockIdx.x & 127) << 8) + tid; // coalesced

    const float s1a = fabsf(s1[0]);
    const float s2a = fabsf(s2[0]);
    const float c1  = LOG2E * s1a;
    const float Ls2 = LOG2E * s2a;

    const float* xb = xyz + b * 3072;
    #pragma unroll
    for (int i = 0; i < 4; ++i) {
        const int n = tid + i * 256;
        const float x = xb[n], y = xb[1024 + n], z = xb[2048 + n];
        const float x2 = fmaf(x, x, fmaf(y, y, z * z));
        A[n] = make_float4(-c1 * x2, 2.f * c1 * x, 2.f * c1 * y, 2.f * c1 * z);
    }
    __syncthreads();

    const float g0 = grid[dhw];
    const float g1 = grid[32768 + dhw];
    const float g2 = grid[65536 + dhw];
    const float EC = LOG2E * s2a *
        __builtin_amdgcn_exp2f(-c1 * fmaf(g0, g0, fmaf(g1, g1, g2 * g2)));

    // parity-split top-2 chains + 4 sum accumulators (ILP)
    float t0E = -INFINITY, t1E = -INFINITY, t0O = -INFINITY, t1O = -INFINITY;
    float S0 = 0.f, S1 = 0.f, S2 = 0.f, S3 = 0.f;

    for (int n0 = 0; n0 < 1024; n0 += 8) {
        // phase L: 8 loads in flight
        float4 r[8];
        #pragma unroll
        for (int j = 0; j < 8; ++j) r[j] = A[n0 + j];
        // phase Q: 8 independent dot products
        float q[8];
        #pragma unroll
        for (int j = 0; j < 8; ++j)
            q[j] = fmaf(g0, r[j].y, fmaf(g1, r[j].z, fmaf(g2, r[j].w, r[j].x)));
        // phase T: top-2 tracking, two parity chains (serial depth 8, not 16)
        #pragma unroll
        for (int j = 0; j < 8; j += 2) {
            t1E = __builtin_amdgcn_fmed3f(t0E, t1E, q[j]);
            t0E = fmaxf(t0E, q[j]);
            t1O = __builtin_amdgcn_fmed3f(t0O, t1O, q[j + 1]);
            t0O = fmaxf(t0O, q[j + 1]);
        }
        // phase E1: 8 INDEPENDENT exps -> pipeline at trans issue rate
        float u[8];
        #pragma unroll
        for (int j = 0; j < 8; ++j) u[j] = __builtin_amdgcn_exp2f(q[j]);
        // phase A: 8 independent fma
        float z[8];
        #pragma unroll
        for (int j = 0; j < 8; ++j) z[j] = fmaf(EC, u[j], -Ls2);
        // phase E2: 8 INDEPENDENT exps
        float w[8];
        #pragma unroll
        for (int j = 0; j < 8; ++j) w[j] = __builtin_amdgcn_exp2f(z[j]);
        // phase S: 4-way accumulate
        S0 += w[0]; S1 += w[1]; S2 += w[2]; S3 += w[3];
        S0 += w[4]; S1 += w[5]; S2 += w[6]; S3 += w[7];
    }

    // merge parity top-2: top0 = max(t0E,t0O); top1 = max(min(t0E,t0O), t1E, t1O)
    const float t0 = fmaxf(t0E, t0O);
    const float t1 = fmaxf(fminf(t0E, t0O), fmaxf(t1E, t1O));
    const float S = (S0 + S1) + (S2 + S3);

    const float u0 = __builtin_amdgcn_exp2f(t0);
    const float u1 = __builtin_amdgcn_exp2f(t1);
    const float w0 = __builtin_amdgcn_exp2f(fmaf(EC, u0, -Ls2)); // exp(v0-|s2|)
    const float num = w0 * (1.f - __builtin_amdgcn_exp2f(EC * (u1 - u0)));
    out[b * 32768 + dhw] = num / S;
}

extern "C" void kernel_launch(void* const* d_in, const int* in_sizes, int n_in,
                              void* d_out, int out_size, void* d_ws, size_t ws_size,
                              hipStream_t stream) {
    const float* xyz  = (const float*)d_in[0];
    const float* grid = (const float*)d_in[1];
    const float* s1   = (const float*)d_in[2];
    const float* s2   = (const float*)d_in[3];
    float* out        = (float*)d_out;
    hipLaunchKernelGGL(p2v_kernel, dim3(512), dim3(256), 0, stream,
                       xyz, grid, s1, s2, out);
}

// Round 8
// 97.541 us; speedup vs baseline: 1.1769x; 1.0181x over previous
//
#include <hip/hip_runtime.h>
#include <math.h>

// P2V: out[b,dhw] = top2-margin over n of softmax_n( |s2| * exp(-|s1| * dist) )
// dist = |x|^2 + |g|^2 - 2 x.g
//
// Round 8: discriminate trans-latency vs trans-issue bound. R7 proved the
// compiler refuses source-level ILP (VGPR stayed 24). So raise TLP instead:
// split each output's n-loop across 4 lanes (n = 4i + lane&3), 2048 blocks
// -> 8 blocks/CU, 32 waves/CU (8/SIMD, was 2/SIMD). Butterfly shfl_xor merge
// of (top0, top1, S) per quad. If exp latency was the stall, dur -> ~30us.
//
// Math (unchanged): q_n = -c1|x_n|^2 + 2c1(x_n.g), c1=log2e*|s1|
//   v_n = Ct*2^q_n, Ct=|s2|*2^(-c1|g|^2); top-2 of v == top-2 of q.
//   S = sum_n 2^(ECt*2^q_n - Ls2)  (shift by bound v<=|s2|; no max pre-pass)
//   out = 2^(ECt*u0 - Ls2)*(1 - 2^(ECt*(u1-u0))) / S.

#define LOG2E 1.44269504088896340736f

__global__ __launch_bounds__(256, 8) void p2v_kernel(
    const float* __restrict__ xyz,   // (B=4, C=3, N=1024)
    const float* __restrict__ grid,  // (C=3, 32768)
    const float* __restrict__ s1,
    const float* __restrict__ s2,
    float* __restrict__ out)         // (B=4, 32768)
{
    __shared__ float4 A[1024];       // 16 KB per-n table for this block's b

    const int tid = threadIdx.x;
    const int b   = blockIdx.x >> 9;                  // 512 blocks per b
    const int k   = blockIdx.x & 511;                 // 64 outputs per block
    const int dhw = (k << 6) + (tid >> 2);            // quad -> one output
    const int c   = tid & 3;                          // n-chunk within quad

    const float s1a = fabsf(s1[0]);
    const float s2a = fabsf(s2[0]);
    const float c1  = LOG2E * s1a;
    const float Ls2 = LOG2E * s2a;

    const float* xb = xyz + b * 3072;
    #pragma unroll
    for (int i = 0; i < 4; ++i) {
        const int n = tid + i * 256;
        const float x = xb[n], y = xb[1024 + n], z = xb[2048 + n];
        const float x2 = fmaf(x, x, fmaf(y, y, z * z));
        A[n] = make_float4(-c1 * x2, 2.f * c1 * x, 2.f * c1 * y, 2.f * c1 * z);
    }
    __syncthreads();

    const float g0 = grid[dhw];
    const float g1 = grid[32768 + dhw];
    const float g2 = grid[65536 + dhw];
    const float EC = LOG2E * s2a *
        __builtin_amdgcn_exp2f(-c1 * fmaf(g0, g0, fmaf(g1, g1, g2 * g2)));

    // this lane covers n = 4*i + c, i in [0,256)
    float t0E = -INFINITY, t1E = -INFINITY, t0O = -INFINITY, t1O = -INFINITY;
    float S0 = 0.f, S1 = 0.f;

    const float4* Ac = A + c;
    #pragma unroll 8
    for (int i = 0; i < 256; ++i) {
        const float4 a = Ac[i << 2];                  // A[4i + c]
        const float q = fmaf(g0, a.y, fmaf(g1, a.z, fmaf(g2, a.w, a.x)));
        if (i & 1) {
            t1O = __builtin_amdgcn_fmed3f(t0O, t1O, q);
            t0O = fmaxf(t0O, q);
        } else {
            t1E = __builtin_amdgcn_fmed3f(t0E, t1E, q);
            t0E = fmaxf(t0E, q);
        }
        const float w = __builtin_amdgcn_exp2f(
            fmaf(EC, __builtin_amdgcn_exp2f(q), -Ls2));
        if (i & 1) S1 += w; else S0 += w;
    }

    // in-lane merge of parity chains
    float t0 = fmaxf(t0E, t0O);
    float t1 = fmaxf(fminf(t0E, t0O), fmaxf(t1E, t1O));
    float S  = S0 + S1;

    // quad butterfly merge (all 4 lanes end with full result)
    #pragma unroll
    for (int m = 1; m <= 2; m <<= 1) {
        const float ot0 = __shfl_xor(t0, m);
        const float ot1 = __shfl_xor(t1, m);
        const float oS  = __shfl_xor(S, m);
        t1 = fmaxf(fminf(t0, ot0), fmaxf(t1, ot1));
        t0 = fmaxf(t0, ot0);
        S += oS;
    }

    if (c == 0) {
        const float u0 = __builtin_amdgcn_exp2f(t0);
        const float u1 = __builtin_amdgcn_exp2f(t1);
        const float w0 = __builtin_amdgcn_exp2f(fmaf(EC, u0, -Ls2)); // exp(v0-|s2|)
        const float num = w0 * (1.f - __builtin_amdgcn_exp2f(EC * (u1 - u0)));
        out[b * 32768 + dhw] = num / S;
    }
}

extern "C" void kernel_launch(void* const* d_in, const int* in_sizes, int n_in,
                              void* d_out, int out_size, void* d_ws, size_t ws_size,
                              hipStream_t stream) {
    const float* xyz  = (const float*)d_in[0];
    const float* grid = (const float*)d_in[1];
    const float* s1   = (const float*)d_in[2];
    const float* s2   = (const float*)d_in[3];
    float* out        = (float*)d_out;
    hipLaunchKernelGGL(p2v_kernel, dim3(2048), dim3(256), 0, stream,
                       xyz, grid, s1, s2, out);
}